// Round 10
// baseline (1698.443 us; speedup 1.0000x reference)
//
#include <hip/hip_runtime.h>
#include <stdint.h>

typedef short bf16x8 __attribute__((ext_vector_type(8)));
typedef float f32x4  __attribute__((ext_vector_type(4)));

#define HH 128
#define NN 448
#define PREDN 96

// ws layout (float offsets)
#define OFF_MEAN 0
#define OFF_STD  448
#define OFF_A    896
#define OFF_B0   1408
#define OFF_B1   1920
#define OFF_H1   2432        // 448*128 floats
#define OFF_XSB  59776       // bf16 xs transposed: 28 blk * 512 t * 16 seq u16
#define OFF_WPK  174464      // packed weight frags: 32 wvmt * 13 slots * 64 lanes * uint4

#define L2E  1.442695041f
#define L2E2 2.885390082f

// h layout (R5-proven): per buffer [16 seq][296 k] bf16, row stride 592 B.
// k: 0..127 = h0, 128..255 = h1, 256 = xs, 257 = 1, rest pad.
#define ROWB 592
#define BUFB 9472            // bytes per buffer; two buffers

__device__ __forceinline__ float bflo(uint32_t w){ union{uint32_t u; float f;} v; v.u = w<<16; return v.f; }
__device__ __forceinline__ float bfhi(uint32_t w){ union{uint32_t u; float f;} v; v.u = w & 0xffff0000u; return v.f; }

static __device__ __forceinline__ uint32_t packbf2(float a, float b){
    union { float f; uint32_t u; } ua, ub; ua.f = a; ub.f = b;
    uint32_t x = ua.u, y = ub.u;
    uint32_t lo = (x + 0x7fffu + ((x>>16)&1u)) >> 16;
    uint32_t hi = (y + 0x7fffu + ((y>>16)&1u)) >> 16;
    return (lo & 0xffffu) | (hi<<16);
}
static __device__ __forceinline__ uint16_t bfr(float f){
    union { float f; uint32_t u; } v; v.f = f;
    return (uint16_t)((v.u + 0x7fffu + ((v.u>>16)&1u)) >> 16);
}

#if __has_builtin(__builtin_amdgcn_exp2f)
#define EXP2(x) __builtin_amdgcn_exp2f(x)
#else
#define EXP2(x) __expf(0.69314718056f*(x))
#endif
#if __has_builtin(__builtin_amdgcn_rcpf)
#define RCPF(x) __builtin_amdgcn_rcpf(x)
#else
#define RCPF(x) (1.0f/(x))
#endif

// preacts pre-scaled by log2e (sigmoid gates) / 2*log2e (tanh gate)
__device__ __forceinline__ float sig2(float x){ return RCPF(1.f + EXP2(-x)); }
__device__ __forceinline__ float tanh2(float xs){ return fmaf(-2.f, RCPF(EXP2(xs) + 1.f), 1.f); }

// ---------------- K1: per-(b,u) mean/std over time ----------------
__global__ void stats_k(const float* __restrict__ x, float* __restrict__ ws){
    int bu = blockIdx.x;
    int b = bu / 7, u = bu % 7;
    int i = threadIdx.x;
    const float* p = x + b*3584 + u;
    float s = 0.f, q = 0.f;
    #pragma unroll
    for (int m=0;m<8;m++){ float v = p[(i + 64*m)*7]; s += v; q += v*v; }
    for (int o=32;o>0;o>>=1){ s += __shfl_down(s,o); q += __shfl_down(q,o); }
    if (i==0){
        float mean = s * (1.f/512.f);
        float var  = q * (1.f/512.f) - mean*mean;
        ws[OFF_MEAN + bu] = mean;
        ws[OFF_STD  + bu] = sqrtf(var + 1e-5f);
    }
}

// ---------------- K2: normalize + write transposed bf16 [blk][t][16] ----------------
__global__ void norm_k(const float* __restrict__ x, float* __restrict__ ws){
    int i = blockIdx.x*256 + threadIdx.x;   // < 229376 exactly
    int b = i / 3584, u = i % 7;
    float m = ws[OFF_MEAN + b*7 + u];
    float sd = ws[OFF_STD + b*7 + u];
    float v = (x[i] - m) / sd;
    int np = i >> 9, tp = i & 511;          // raw-reshape row/col
    uint16_t* xb = (uint16_t*)(ws + OFF_XSB);
    xb[(np>>4)*8192 + tp*16 + (np&15)] = (uint16_t)(packbf2(v, 0.f) & 0xffffu);
}

// ---------------- K3: A' = Wih0@embW, B0', B1' ----------------
__global__ void prep_k(const float* __restrict__ Wih, const float* __restrict__ embW,
                       const float* __restrict__ embb, const float* __restrict__ bih,
                       const float* __restrict__ bhh, float* __restrict__ ws){
    int g = threadIdx.x;
    const float* wr = Wih + g*HH;
    float a = 0.f, bb = 0.f;
    #pragma unroll 4
    for (int k=0;k<HH;k++){ a += wr[k]*embW[k]; bb += wr[k]*embb[k]; }
    ws[OFF_A  + g] = a;
    ws[OFF_B0 + g] = bb + bih[g] + bhh[g];
    ws[OFF_B1 + g] = bih[512 + g] + bhh[512 + g];
}

// ---------------- K3b: pre-pack weight frags (R5 version: consecutive-k, pre-scaled) ----
// slot 0..3 = Whh L0, slot 4 = aug (A',B0'), slot 5..8 = Wih L1, 9..12 = Whh L1
__global__ void prep2_k(const float* __restrict__ Whh, const float* __restrict__ Wih,
                        float* __restrict__ ws){
    int idx = blockIdx.x*256 + threadIdx.x;   // 0..26623
    int lane = idx & 63;
    int sg = idx >> 6;                        // 0..415
    int wvmt = sg / 13, slot = sg % 13;
    int gp  = wvmt*16 + (lane&15);
    int type = gp & 3, unit = gp >> 2;
    int row = type*128 + unit;
    float S = (type==2) ? L2E2 : L2E;
    uint4 r;
    if (slot == 4){
        r.x = r.y = r.z = r.w = 0u;
        if ((lane>>4) == 0) r.x = packbf2(ws[OFF_A+row]*S, ws[OFF_B0+row]*S);
    } else {
        const float* src; int kk;
        if (slot < 4)      { src = Whh + row*128;         kk = slot;   }
        else if (slot < 9) { src = Wih + 65536 + row*128; kk = slot-5; }
        else               { src = Whh + 65536 + row*128; kk = slot-9; }
        int k0 = kk*32 + (lane>>4)*8;
        r.x = packbf2(src[k0]*S,   src[k0+1]*S);
        r.y = packbf2(src[k0+2]*S, src[k0+3]*S);
        r.z = packbf2(src[k0+4]*S, src[k0+5]*S);
        r.w = packbf2(src[k0+6]*S, src[k0+7]*S);
    }
    ((uint4*)(ws + OFF_WPK))[sg*64 + lane] = r;
}

// ---------------- K4: persistent MFMA LSTM, two-phase (R5) + g->f register carry -------
union FragU { bf16x8 v; uint4 q; };

__device__ __forceinline__ f32x4 mm(bf16x8 a, bf16x8 b, f32x4 c){
    return __builtin_amdgcn_mfma_f32_16x16x32_bf16(a, b, c, 0, 0, 0);
}
#define LD(p) (*(const bf16x8*)(p))

__global__ __launch_bounds__(512, 2) void lstm_core(float* __restrict__ ws)
{
    __shared__ uint16_t xsT[8192];                      // bf16 [512 t][16 seq]
    __shared__ __align__(16) uint16_t hbuf[BUFB];       // 2 buffers, BUFB bytes each

    const int tid = threadIdx.x;
    const int wv = tid>>6, l = tid&63;
    const int r   = l & 15;                 // seq within block
    const int q   = l >> 4;                 // k-subgroup
    const int bx = blockIdx.x, n0 = bx*16;
    char* hb = (char*)hbuf;

    const uint16_t* xb = (const uint16_t*)(ws + OFF_XSB) + bx*8192;
    for (int i=tid;i<8192;i+=512) xsT[i] = xb[i];
    for (int i=tid;i<BUFB;i+=512) hbuf[i] = 0;          // zero both buffers
    __syncthreads();    // zero-fill + xsT visible before special rows (R2 race lesson)
    if (tid < 32){
        int bsel = tid>>4, rr = tid&15;
        *(uint16_t*)(hb + bsel*BUFB + rr*ROWB + 514) = 0x3F80;   // k=257 const-1, both bufs
    }
    if (tid < 16){
        *(uint16_t*)(hb + tid*ROWB + 512) = xsT[tid];            // xs_0 at k=256, buf0
    }

    // ---- resident weights: pre-packed, pre-scaled bf16 frags (R5 layout) ----
    bf16x8 wL0[4][5], wI1[4][4], wH1[4][4];
    uint32_t b1pk[4][2];
    const uint4* wpk = (const uint4*)(ws + OFF_WPK);
    #pragma unroll
    for (int mt=0;mt<4;++mt){
        int base = ((wv*4+mt)*13)*64 + l;
        #pragma unroll
        for (int kk=0;kk<5;kk++){ FragU u; u.q = wpk[base + kk*64];     wL0[mt][kk]=u.v; }
        #pragma unroll
        for (int kk=0;kk<4;kk++){ FragU u; u.q = wpk[base + (5+kk)*64]; wI1[mt][kk]=u.v; }
        #pragma unroll
        for (int kk=0;kk<4;kk++){ FragU u; u.q = wpk[base + (9+kk)*64]; wH1[mt][kk]=u.v; }
        int uu = (wv*4+mt)*4 + q;
        b1pk[mt][0] = packbf2(ws[OFF_B1+uu]*L2E,      ws[OFF_B1+128+uu]*L2E);
        b1pk[mt][1] = packbf2(ws[OFF_B1+256+uu]*L2E2, ws[OFF_B1+384+uu]*L2E);
    }

    float c0[4]={0,0,0,0}, c1[4]={0,0,0,0};
    const int rbase = r*ROWB + q*16;                 // read base within a buffer
    const int wbase = r*ROWB + wv*32 + 2*q;          // b16 write base (R5 layout)

    // carried h0 fragments: h0[t-1] in phase 1 == phase 2's previous loads.
    bf16x8 f0 = {0,0,0,0,0,0,0,0}, f1 = {0,0,0,0,0,0,0,0};
    bf16x8 f2 = {0,0,0,0,0,0,0,0}, f3 = {0,0,0,0,0,0,0,0};

    __syncthreads();

    for (int t=0;t<512;++t){
        const int co = (t&1)*BUFB;
        const int no = BUFB - co;
        const char* pc = hb + co + rbase;
        const char* pn = hb + no + rbase;
        char* pw = hb + no + wbase;

        // ================= phase 1: layer 0 (f0..f3 carried; only aug read) =========
        {
            bf16x8 fa = LD(pc+512);
            f32x4 a0={0,0,0,0}, a1={0,0,0,0}, a2={0,0,0,0}, a3={0,0,0,0};
            a0=mm(wL0[0][0],f0,a0); a1=mm(wL0[1][0],f0,a1); a2=mm(wL0[2][0],f0,a2); a3=mm(wL0[3][0],f0,a3);
            a0=mm(wL0[0][1],f1,a0); a1=mm(wL0[1][1],f1,a1); a2=mm(wL0[2][1],f1,a2); a3=mm(wL0[3][1],f1,a3);
            a0=mm(wL0[0][2],f2,a0); a1=mm(wL0[1][2],f2,a1); a2=mm(wL0[2][2],f2,a2); a3=mm(wL0[3][2],f2,a3);
            a0=mm(wL0[0][3],f3,a0); a1=mm(wL0[1][3],f3,a1); a2=mm(wL0[2][3],f3,a2); a3=mm(wL0[3][3],f3,a3);
            a0=mm(wL0[0][4],fa,a0); a1=mm(wL0[1][4],fa,a1); a2=mm(wL0[2][4],fa,a2); a3=mm(wL0[3][4],fa,a3);
            #pragma unroll
            for (int mt=0;mt<4;++mt){
                f32x4 a = (mt==0)?a0:(mt==1)?a1:(mt==2)?a2:a3;
                float i_ = sig2(a[0]);
                float f_ = sig2(a[1]);
                float g_ = tanh2(a[2]);
                float o_ = sig2(a[3]);
                float cn = fmaf(f_, c0[mt], i_*g_);
                c0[mt] = cn;
                float h = o_ * tanh2(cn*L2E2);
                *(uint16_t*)(pw + 8*mt) = bfr(h);     // h0[t] -> next buf
            }
        }
        if (wv==0 && l<16){
            *(uint16_t*)(hb + no + l*ROWB + 512) = xsT[((t+1)&511)*16 + l];  // xs[t+1]
        }
        __syncthreads();

        // ================= phase 2: layer 1 (loads h0[t] into f0..f3 = next carry) ====
        {
            f0 = LD(pn+0); f1 = LD(pn+64); f2 = LD(pn+128); f3 = LD(pn+192);
            bf16x8 v0 = LD(pc+256), v1 = LD(pc+320), v2 = LD(pc+384), v3 = LD(pc+448);
            f32x4 b0={0,0,0,0}, b1={0,0,0,0}, b2={0,0,0,0}, b3={0,0,0,0};
            b0=mm(wI1[0][0],f0,b0); b1=mm(wI1[1][0],f0,b1); b2=mm(wI1[2][0],f0,b2); b3=mm(wI1[3][0],f0,b3);
            b0=mm(wI1[0][1],f1,b0); b1=mm(wI1[1][1],f1,b1); b2=mm(wI1[2][1],f1,b2); b3=mm(wI1[3][1],f1,b3);
            b0=mm(wI1[0][2],f2,b0); b1=mm(wI1[1][2],f2,b1); b2=mm(wI1[2][2],f2,b2); b3=mm(wI1[3][2],f2,b3);
            b0=mm(wI1[0][3],f3,b0); b1=mm(wI1[1][3],f3,b1); b2=mm(wI1[2][3],f3,b2); b3=mm(wI1[3][3],f3,b3);
            b0=mm(wH1[0][0],v0,b0); b1=mm(wH1[1][0],v0,b1); b2=mm(wH1[2][0],v0,b2); b3=mm(wH1[3][0],v0,b3);
            b0=mm(wH1[0][1],v1,b0); b1=mm(wH1[1][1],v1,b1); b2=mm(wH1[2][1],v1,b2); b3=mm(wH1[3][1],v1,b3);
            b0=mm(wH1[0][2],v2,b0); b1=mm(wH1[1][2],v2,b1); b2=mm(wH1[2][2],v2,b2); b3=mm(wH1[3][2],v2,b3);
            b0=mm(wH1[0][3],v3,b0); b1=mm(wH1[1][3],v3,b1); b2=mm(wH1[2][3],v3,b2); b3=mm(wH1[3][3],v3,b3);
            #pragma unroll
            for (int mt=0;mt<4;++mt){
                f32x4 a = (mt==0)?b0:(mt==1)?b1:(mt==2)?b2:b3;
                float i_ = sig2(a[0] + bflo(b1pk[mt][0]));
                float f_ = sig2(a[1] + bfhi(b1pk[mt][0]));
                float g_ = tanh2(a[2] + bflo(b1pk[mt][1]));
                float o_ = sig2(a[3] + bfhi(b1pk[mt][1]));
                float cn = fmaf(f_, c1[mt], i_*g_);
                c1[mt] = cn;
                float h = o_ * tanh2(cn*L2E2);
                *(uint16_t*)(pw + 256 + 8*mt) = bfr(h);   // h1[t] -> next buf
                if (t==511) ws[OFF_H1 + (n0+r)*128 + (wv*16 + mt*4 + q)] = h;
            }
        }
        __syncthreads();
    }
}

// ---------------- K5: FC head + de-normalization ----------------
__global__ void out_k(const float* __restrict__ fcW, const float* __restrict__ fcb,
                      const float* __restrict__ ws, float* __restrict__ out){
    __shared__ float hl[128];
    int n = blockIdx.x, tid = threadIdx.x;
    hl[tid] = ws[OFF_H1 + n*128 + tid];
    __syncthreads();
    if (tid < PREDN){
        float acc = fcb[tid];
        const float* wr = fcW + tid*128;
        #pragma unroll 4
        for (int k=0;k<128;k++) acc += wr[k]*hl[k];
        int idx = n*PREDN + tid;
        int b = idx / 672, u = idx % 7;
        out[idx] = acc * ws[OFF_STD + b*7 + u] + ws[OFF_MEAN + b*7 + u];
    }
}

extern "C" void kernel_launch(void* const* d_in, const int* in_sizes, int n_in,
                              void* d_out, int out_size, void* d_ws, size_t ws_size,
                              hipStream_t stream)
{
    const float* x    = (const float*)d_in[0];
    const float* embW = (const float*)d_in[1];
    const float* embb = (const float*)d_in[2];
    const float* Wih  = (const float*)d_in[3];
    const float* Whh  = (const float*)d_in[4];
    const float* bih  = (const float*)d_in[5];
    const float* bhh  = (const float*)d_in[6];
    const float* fcW  = (const float*)d_in[7];
    const float* fcb  = (const float*)d_in[8];
    float* ws  = (float*)d_ws;
    float* out = (float*)d_out;

    stats_k<<<448, 64, 0, stream>>>(x, ws);
    norm_k<<<896, 256, 0, stream>>>(x, ws);
    prep_k<<<1, 512, 0, stream>>>(Wih, embW, embb, bih, bhh, ws);
    prep2_k<<<104, 256, 0, stream>>>(Whh, Wih, ws);
    lstm_core<<<28, 512, 0, stream>>>(ws);
    out_k<<<NN, 128, 0, stream>>>(fcW, fcb, ws, out);
}

// Round 11
// 1002.377 us; speedup vs baseline: 1.6944x; 1.6944x over previous
//
#include <hip/hip_runtime.h>
#include <stdint.h>

typedef short bf16x8 __attribute__((ext_vector_type(8)));
typedef float f32x4  __attribute__((ext_vector_type(4)));

#define HH 128
#define NN 448
#define PREDN 96

// ws layout (float offsets)
#define OFF_MEAN 0
#define OFF_STD  448
#define OFF_A    896
#define OFF_B0   1408
#define OFF_B1   1920
#define OFF_H1   2432        // 448*128 floats
#define OFF_XSB  59776       // bf16 xs transposed: 28 blk * 512 t * 16 seq u16
#define OFF_WPK  174464      // packed weight frags: 32 wvmt * 13 slots * 64 lanes * uint4

#define L2E  1.442695041f
#define L2E2 2.885390082f

// h layout: per buffer [16 seq][296 k] bf16, row stride 592 B.
// 592/4 = 148 dwords, 148 % 32 = 20 -> 2-way bank aliasing (free per m136).
// k: 0..127 = h0, 128..255 = h1, 256 = xs, 257 = 1, 258..295 = zero pad.
// NOTE (R6-R10 lesson): this two-phase / two-__syncthreads structure is the ONLY
// variant that fits the register budget (128 VGPR + 128 AGPR, zero slack).
// Merged phases, b64 write permutes, lagged L1, and cross-barrier register
// carries ALL spill to scratch (WRITE_SIZE balloons) and regress 15-75%.
#define ROWB 592
#define BUFB 9472            // bytes per buffer; two buffers

__device__ __forceinline__ float bflo(uint32_t w){ union{uint32_t u; float f;} v; v.u = w<<16; return v.f; }
__device__ __forceinline__ float bfhi(uint32_t w){ union{uint32_t u; float f;} v; v.u = w & 0xffff0000u; return v.f; }

static __device__ __forceinline__ uint32_t packbf2(float a, float b){
    union { float f; uint32_t u; } ua, ub; ua.f = a; ub.f = b;
    uint32_t x = ua.u, y = ub.u;
    uint32_t lo = (x + 0x7fffu + ((x>>16)&1u)) >> 16;
    uint32_t hi = (y + 0x7fffu + ((y>>16)&1u)) >> 16;
    return (lo & 0xffffu) | (hi<<16);
}
static __device__ __forceinline__ uint16_t bfr(float f){
    union { float f; uint32_t u; } v; v.f = f;
    return (uint16_t)((v.u + 0x7fffu + ((v.u>>16)&1u)) >> 16);
}

#if __has_builtin(__builtin_amdgcn_exp2f)
#define EXP2(x) __builtin_amdgcn_exp2f(x)
#else
#define EXP2(x) __expf(0.69314718056f*(x))
#endif
#if __has_builtin(__builtin_amdgcn_rcpf)
#define RCPF(x) __builtin_amdgcn_rcpf(x)
#else
#define RCPF(x) (1.0f/(x))
#endif

// preacts pre-scaled by log2e (sigmoid gates) / 2*log2e (tanh gate)
__device__ __forceinline__ float sig2(float x){ return RCPF(1.f + EXP2(-x)); }
__device__ __forceinline__ float tanh2(float xs){ return fmaf(-2.f, RCPF(EXP2(xs) + 1.f), 1.f); }

// ---------------- K1: per-(b,u) mean/std over time ----------------
__global__ void stats_k(const float* __restrict__ x, float* __restrict__ ws){
    int bu = blockIdx.x;
    int b = bu / 7, u = bu % 7;
    int i = threadIdx.x;
    const float* p = x + b*3584 + u;
    float s = 0.f, q = 0.f;
    #pragma unroll
    for (int m=0;m<8;m++){ float v = p[(i + 64*m)*7]; s += v; q += v*v; }
    for (int o=32;o>0;o>>=1){ s += __shfl_down(s,o); q += __shfl_down(q,o); }
    if (i==0){
        float mean = s * (1.f/512.f);
        float var  = q * (1.f/512.f) - mean*mean;
        ws[OFF_MEAN + bu] = mean;
        ws[OFF_STD  + bu] = sqrtf(var + 1e-5f);
    }
}

// ---------------- K2: normalize + write transposed bf16 [blk][t][16] ----------------
__global__ void norm_k(const float* __restrict__ x, float* __restrict__ ws){
    int i = blockIdx.x*256 + threadIdx.x;   // < 229376 exactly
    int b = i / 3584, u = i % 7;
    float m = ws[OFF_MEAN + b*7 + u];
    float sd = ws[OFF_STD + b*7 + u];
    float v = (x[i] - m) / sd;
    int np = i >> 9, tp = i & 511;          // raw-reshape row/col
    uint16_t* xb = (uint16_t*)(ws + OFF_XSB);
    xb[(np>>4)*8192 + tp*16 + (np&15)] = (uint16_t)(packbf2(v, 0.f) & 0xffffu);
}

// ---------------- K3: A' = Wih0@embW, B0', B1' (raw; scaled at pack time) ------------
__global__ void prep_k(const float* __restrict__ Wih, const float* __restrict__ embW,
                       const float* __restrict__ embb, const float* __restrict__ bih,
                       const float* __restrict__ bhh, float* __restrict__ ws){
    int g = threadIdx.x;
    const float* wr = Wih + g*HH;
    float a = 0.f, bb = 0.f;
    #pragma unroll 4
    for (int k=0;k<HH;k++){ a += wr[k]*embW[k]; bb += wr[k]*embb[k]; }
    ws[OFF_A  + g] = a;
    ws[OFF_B0 + g] = bb + bih[g] + bhh[g];
    ws[OFF_B1 + g] = bih[512 + g] + bhh[512 + g];
}

// ---------------- K3b: pre-pack weight frags (bf16, consecutive-k, pre-scaled) --------
// slot 0..3 = Whh L0, slot 4 = aug (A',B0'), slot 5..8 = Wih L1, 9..12 = Whh L1
__global__ void prep2_k(const float* __restrict__ Whh, const float* __restrict__ Wih,
                        float* __restrict__ ws){
    int idx = blockIdx.x*256 + threadIdx.x;   // 0..26623
    int lane = idx & 63;
    int sg = idx >> 6;                        // 0..415
    int wvmt = sg / 13, slot = sg % 13;
    int gp  = wvmt*16 + (lane&15);
    int type = gp & 3, unit = gp >> 2;
    int row = type*128 + unit;
    float S = (type==2) ? L2E2 : L2E;
    uint4 r;
    if (slot == 4){
        r.x = r.y = r.z = r.w = 0u;
        if ((lane>>4) == 0) r.x = packbf2(ws[OFF_A+row]*S, ws[OFF_B0+row]*S);
    } else {
        const float* src; int kk;
        if (slot < 4)      { src = Whh + row*128;         kk = slot;   }
        else if (slot < 9) { src = Wih + 65536 + row*128; kk = slot-5; }
        else               { src = Whh + 65536 + row*128; kk = slot-9; }
        int k0 = kk*32 + (lane>>4)*8;
        r.x = packbf2(src[k0]*S,   src[k0+1]*S);
        r.y = packbf2(src[k0+2]*S, src[k0+3]*S);
        r.z = packbf2(src[k0+4]*S, src[k0+5]*S);
        r.w = packbf2(src[k0+6]*S, src[k0+7]*S);
    }
    ((uint4*)(ws + OFF_WPK))[sg*64 + lane] = r;
}

// ---------------- K4: persistent MFMA LSTM, 28 blocks x 16 seq (R5, proven) ----------
union FragU { bf16x8 v; uint4 q; };

__device__ __forceinline__ f32x4 mm(bf16x8 a, bf16x8 b, f32x4 c){
    return __builtin_amdgcn_mfma_f32_16x16x32_bf16(a, b, c, 0, 0, 0);
}
#define LD(p) (*(const bf16x8*)(p))

__global__ __launch_bounds__(512, 2) void lstm_core(float* __restrict__ ws)
{
    __shared__ uint16_t xsT[8192];                      // bf16 [512 t][16 seq]
    __shared__ __align__(16) uint16_t hbuf[BUFB];       // 2 buffers, BUFB bytes each

    const int tid = threadIdx.x;
    const int wv = tid>>6, l = tid&63;
    const int r   = l & 15;                 // seq within block
    const int q16 = (l>>4)*16;              // k-subgroup byte offset
    const int bx = blockIdx.x, n0 = bx*16;
    char* hb = (char*)hbuf;

    const uint16_t* xb = (const uint16_t*)(ws + OFF_XSB) + bx*8192;
    for (int i=tid;i<8192;i+=512) xsT[i] = xb[i];
    for (int i=tid;i<BUFB;i+=512) hbuf[i] = 0;          // zero both buffers
    __syncthreads();    // zero-fill + xsT visible before special rows (R2 race lesson)
    if (tid < 32){
        int bsel = tid>>4, rr = tid&15;
        *(uint16_t*)(hb + bsel*BUFB + rr*ROWB + 514) = 0x3F80;   // k=257 const-1, both bufs
    }
    if (tid < 16){
        *(uint16_t*)(hb + tid*ROWB + 512) = xsT[tid];            // xs_0 at k=256, buf0
    }

    // ---- resident weights: pre-packed, pre-scaled bf16 frags ----
    bf16x8 wL0[4][5], wI1[4][4], wH1[4][4];
    uint32_t b1pk[4][2];
    const uint4* wpk = (const uint4*)(ws + OFF_WPK);
    #pragma unroll
    for (int mt=0;mt<4;++mt){
        int base = ((wv*4+mt)*13)*64 + l;
        #pragma unroll
        for (int kk=0;kk<5;kk++){ FragU u; u.q = wpk[base + kk*64];     wL0[mt][kk]=u.v; }
        #pragma unroll
        for (int kk=0;kk<4;kk++){ FragU u; u.q = wpk[base + (5+kk)*64]; wI1[mt][kk]=u.v; }
        #pragma unroll
        for (int kk=0;kk<4;kk++){ FragU u; u.q = wpk[base + (9+kk)*64]; wH1[mt][kk]=u.v; }
        int uu = (wv*4+mt)*4 + (l>>4);
        b1pk[mt][0] = packbf2(ws[OFF_B1+uu]*L2E,      ws[OFF_B1+128+uu]*L2E);
        b1pk[mt][1] = packbf2(ws[OFF_B1+256+uu]*L2E2, ws[OFF_B1+384+uu]*L2E);
    }

    float c0[4]={0,0,0,0}, c1[4]={0,0,0,0};
    const int rbase = r*ROWB + q16;                  // read base within a buffer
    const int wbase = r*ROWB + wv*32 + 2*(l>>4);     // b16 write base; mt adds 8*mt

    __syncthreads();

    for (int t=0;t<512;++t){
        const int co = (t&1)*BUFB;
        const int no = BUFB - co;
        const char* pc = hb + co + rbase;
        const char* pn = hb + no + rbase;
        char* pw = hb + no + wbase;

        // ================= phase 1: layer 0 =================
        {
            bf16x8 f0 = LD(pc+0), f1 = LD(pc+64), f2 = LD(pc+128), f3 = LD(pc+192), fa = LD(pc+512);
            f32x4 a0={0,0,0,0}, a1={0,0,0,0}, a2={0,0,0,0}, a3={0,0,0,0};
            a0=mm(wL0[0][0],f0,a0); a1=mm(wL0[1][0],f0,a1); a2=mm(wL0[2][0],f0,a2); a3=mm(wL0[3][0],f0,a3);
            a0=mm(wL0[0][1],f1,a0); a1=mm(wL0[1][1],f1,a1); a2=mm(wL0[2][1],f1,a2); a3=mm(wL0[3][1],f1,a3);
            a0=mm(wL0[0][2],f2,a0); a1=mm(wL0[1][2],f2,a1); a2=mm(wL0[2][2],f2,a2); a3=mm(wL0[3][2],f2,a3);
            a0=mm(wL0[0][3],f3,a0); a1=mm(wL0[1][3],f3,a1); a2=mm(wL0[2][3],f3,a2); a3=mm(wL0[3][3],f3,a3);
            a0=mm(wL0[0][4],fa,a0); a1=mm(wL0[1][4],fa,a1); a2=mm(wL0[2][4],fa,a2); a3=mm(wL0[3][4],fa,a3);
            #pragma unroll
            for (int mt=0;mt<4;++mt){
                f32x4 a = (mt==0)?a0:(mt==1)?a1:(mt==2)?a2:a3;
                float i_ = sig2(a[0]);
                float f_ = sig2(a[1]);
                float g_ = tanh2(a[2]);
                float o_ = sig2(a[3]);
                float cn = fmaf(f_, c0[mt], i_*g_);
                c0[mt] = cn;
                float h = o_ * tanh2(cn*L2E2);
                *(uint16_t*)(pw + 8*mt) = bfr(h);
            }
        }
        __syncthreads();

        // ================= phase 2: layer 1 (K = h0 new | h1 cur) =================
        {
            bf16x8 g0 = LD(pn+0),   g1 = LD(pn+64),  g2 = LD(pn+128), g3 = LD(pn+192);
            bf16x8 v0 = LD(pc+256), v1 = LD(pc+320), v2 = LD(pc+384), v3 = LD(pc+448);
            f32x4 b0={0,0,0,0}, b1={0,0,0,0}, b2={0,0,0,0}, b3={0,0,0,0};
            b0=mm(wI1[0][0],g0,b0); b1=mm(wI1[1][0],g0,b1); b2=mm(wI1[2][0],g0,b2); b3=mm(wI1[3][0],g0,b3);
            b0=mm(wI1[0][1],g1,b0); b1=mm(wI1[1][1],g1,b1); b2=mm(wI1[2][1],g1,b2); b3=mm(wI1[3][1],g1,b3);
            b0=mm(wI1[0][2],g2,b0); b1=mm(wI1[1][2],g2,b1); b2=mm(wI1[2][2],g2,b2); b3=mm(wI1[3][2],g2,b3);
            b0=mm(wI1[0][3],g3,b0); b1=mm(wI1[1][3],g3,b1); b2=mm(wI1[2][3],g3,b2); b3=mm(wI1[3][3],g3,b3);
            b0=mm(wH1[0][0],v0,b0); b1=mm(wH1[1][0],v0,b1); b2=mm(wH1[2][0],v0,b2); b3=mm(wH1[3][0],v0,b3);
            b0=mm(wH1[0][1],v1,b0); b1=mm(wH1[1][1],v1,b1); b2=mm(wH1[2][1],v1,b2); b3=mm(wH1[3][1],v1,b3);
            b0=mm(wH1[0][2],v2,b0); b1=mm(wH1[1][2],v2,b1); b2=mm(wH1[2][2],v2,b2); b3=mm(wH1[3][2],v2,b3);
            b0=mm(wH1[0][3],v3,b0); b1=mm(wH1[1][3],v3,b1); b2=mm(wH1[2][3],v3,b2); b3=mm(wH1[3][3],v3,b3);
            #pragma unroll
            for (int mt=0;mt<4;++mt){
                f32x4 a = (mt==0)?b0:(mt==1)?b1:(mt==2)?b2:b3;
                float i_ = sig2(a[0] + bflo(b1pk[mt][0]));
                float f_ = sig2(a[1] + bfhi(b1pk[mt][0]));
                float g_ = tanh2(a[2] + bflo(b1pk[mt][1]));
                float o_ = sig2(a[3] + bfhi(b1pk[mt][1]));
                float cn = fmaf(f_, c1[mt], i_*g_);
                c1[mt] = cn;
                float h = o_ * tanh2(cn*L2E2);
                *(uint16_t*)(pw + 256 + 8*mt) = bfr(h);
                if (t==511) ws[OFF_H1 + (n0+r)*128 + (wv*16 + mt*4 + (l>>4))] = h;
            }
        }
        if (wv==0 && l<16){
            *(uint16_t*)(hb + no + l*ROWB + 512) = xsT[((t+1)&511)*16 + l];  // xs for next step
        }
        __syncthreads();
    }
}

// ---------------- K5: FC head + de-normalization ----------------
__global__ void out_k(const float* __restrict__ fcW, const float* __restrict__ fcb,
                      const float* __restrict__ ws, float* __restrict__ out){
    __shared__ float hl[128];
    int n = blockIdx.x, tid = threadIdx.x;
    hl[tid] = ws[OFF_H1 + n*128 + tid];
    __syncthreads();
    if (tid < PREDN){
        float acc = fcb[tid];
        const float* wr = fcW + tid*128;
        #pragma unroll 4
        for (int k=0;k<128;k++) acc += wr[k]*hl[k];
        int idx = n*PREDN + tid;
        int b = idx / 672, u = idx % 7;
        out[idx] = acc * ws[OFF_STD + b*7 + u] + ws[OFF_MEAN + b*7 + u];
    }
}

extern "C" void kernel_launch(void* const* d_in, const int* in_sizes, int n_in,
                              void* d_out, int out_size, void* d_ws, size_t ws_size,
                              hipStream_t stream)
{
    const float* x    = (const float*)d_in[0];
    const float* embW = (const float*)d_in[1];
    const float* embb = (const float*)d_in[2];
    const float* Wih  = (const float*)d_in[3];
    const float* Whh  = (const float*)d_in[4];
    const float* bih  = (const float*)d_in[5];
    const float* bhh  = (const float*)d_in[6];
    const float* fcW  = (const float*)d_in[7];
    const float* fcb  = (const float*)d_in[8];
    float* ws  = (float*)d_ws;
    float* out = (float*)d_out;

    stats_k<<<448, 64, 0, stream>>>(x, ws);
    norm_k<<<896, 256, 0, stream>>>(x, ws);
    prep_k<<<1, 512, 0, stream>>>(Wih, embW, embb, bih, bhh, ws);
    prep2_k<<<104, 256, 0, stream>>>(Whh, Wih, ws);
    lstm_core<<<28, 512, 0, stream>>>(ws);
    out_k<<<NN, 128, 0, stream>>>(fcW, fcb, ws, out);
}